// Round 10
// baseline (287.435 us; speedup 1.0000x reference)
//
#include <hip/hip_runtime.h>
#include <hip/hip_bf16.h>
#include <stdint.h>

#define DIN 2048
#define DEMB 1024
#define NSUP 2048
#define NQRY 16384
#define NWAY 64

typedef __attribute__((ext_vector_type(8))) short bf16x8;
typedef __attribute__((ext_vector_type(4))) float f32x4;

__device__ inline unsigned short f2bf(float f) {
    union { float f; uint32_t u; } v; v.f = f;
    uint32_t u = v.u;
    uint32_t r = (u + 0x7FFFu + ((u >> 16) & 1u)) >> 16;
    return (unsigned short)r;
}

// ---------------- conversion kernels ----------------

__global__ void cvt_f32_bf16(const float* __restrict__ in, unsigned short* __restrict__ out, int n) {
    int i = (blockIdx.x * blockDim.x + threadIdx.x) * 4;
    int stride = gridDim.x * blockDim.x * 4;
    for (; i < n; i += stride) {
        float4 v = *(const float4*)(in + i);
        ushort4 o;
        o.x = f2bf(v.x); o.y = f2bf(v.y); o.z = f2bf(v.z); o.w = f2bf(v.w);
        *(ushort4*)(out + i) = o;
    }
}

// W [DIN][DEMB] f32  ->  Wt [DEMB][DIN] bf16
__global__ void cvt_transpose(const float* __restrict__ W, unsigned short* __restrict__ Wt) {
    __shared__ float tile[32][33];
    int c0 = blockIdx.x * 32;   // col in W
    int r0 = blockIdx.y * 32;   // row in W
    int tc = threadIdx.x & 31, tr = threadIdx.x >> 5;  // tr 0..7
    #pragma unroll
    for (int i = 0; i < 4; i++)
        tile[tr + 8*i][tc] = W[(size_t)(r0 + tr + 8*i) * DEMB + c0 + tc];
    __syncthreads();
    #pragma unroll
    for (int i = 0; i < 4; i++)
        Wt[(size_t)(c0 + tr + 8*i) * DIN + r0 + tc] = f2bf(tile[tc][tr + 8*i]);
}

// ---------------- embedding GEMM: 128x128 tile, BK=32, 3-stage counted-vmcnt pipeline ----
// C[M][DEMB] = A[M][DIN](bf16) @ Wt[DEMB][DIN]^T + bias
// T4 deep schedule: issue stage(t+2), wait vmcnt(8) -- two stages (8 loads) stay in
// flight across the barrier, 2-iteration (~600 cyc) lookahead hides HBM-miss latency.
// Buffer safety: stage(t+2) overwrites buf[(t-1)%3]; all reads of tile t-1 retired
// before iter t-1's trailing barrier, which precedes this issue. 48 KB LDS.
// EPILOGUE 0: support -> atomicAdd proto_sums[label[row]][col]
// EPILOGUE 1: query   -> store bf16 emb + atomicAdd row sumsq

#define ISSUE4(la, lb, gaP, gbP) do {                                                              \
    __builtin_amdgcn_global_load_lds((const __attribute__((address_space(1))) void*)(gaP),         \
                                     (__attribute__((address_space(3))) void*)(la), 16, 0, 0);     \
    __builtin_amdgcn_global_load_lds((const __attribute__((address_space(1))) void*)((gaP) + 16),  \
                                     (__attribute__((address_space(3))) void*)((la) + 2048), 16, 0, 0); \
    __builtin_amdgcn_global_load_lds((const __attribute__((address_space(1))) void*)(gbP),         \
                                     (__attribute__((address_space(3))) void*)(lb), 16, 0, 0);     \
    __builtin_amdgcn_global_load_lds((const __attribute__((address_space(1))) void*)((gbP) + 16),  \
                                     (__attribute__((address_space(3))) void*)((lb) + 2048), 16, 0, 0); \
} while (0)

template<int EPILOGUE>
__global__ __launch_bounds__(256) void gemm_emb(
    const unsigned short* __restrict__ A,
    const unsigned short* __restrict__ Bt,
    const float* __restrict__ bias,
    const int* __restrict__ labels,
    float* __restrict__ proto_sums,
    unsigned short* __restrict__ emb_out,
    float* __restrict__ qsq)
{
    // triple-buffered, kgrp-major (conflict-free, matches global_load_lds linear dest)
    // per-buffer: [4][128][8] ushort = 4096 elements = 8 KB
    __shared__ __attribute__((aligned(16))) unsigned short AsF[3 * 4096];
    __shared__ __attribute__((aligned(16))) unsigned short BsF[3 * 4096];

    const int tid = threadIdx.x;
    const int nblk = DEMB / 128;            // 8
    // XCD-panel grouping (verified r8: FETCH 268->66MB). gridDim.x % 8 == 0.
    const int h = blockIdx.x;
    const int cpx = (int)(gridDim.x >> 3);
    const int wg = (h & 7) * cpx + (h >> 3);
    const int bx = wg % nblk;
    const int by = wg / nblk;
    const int brow = by * 128, bcol = bx * 128;
    const int lane = tid & 63, wid = tid >> 6;
    const int wr = wid >> 1, wc = wid & 1;

    // hoisted staging addresses: thread tid handles LDS 16B slot tid (p=0) and 256+tid (p=1).
    const int row0 = tid & 127, kgs0 = tid >> 7;      // kgs0 in 0..1
    const unsigned short* ga = A  + (size_t)(brow + row0) * DIN + kgs0 * 8;
    const unsigned short* gb = Bt + (size_t)(bcol + row0) * DIN + kgs0 * 8;

    f32x4 acc[4][4];
    #pragma unroll
    for (int i = 0; i < 4; i++)
        #pragma unroll
        for (int j = 0; j < 4; j++) acc[i][j] = (f32x4)(0.f);

    // prologue: stage tiles 0 and 1 into bufs 0 and 1
    ISSUE4(AsF + tid * 8, BsF + tid * 8, ga, gb);
    ga += 32; gb += 32;
    ISSUE4(AsF + 4096 + tid * 8, BsF + 4096 + tid * 8, ga, gb);
    ga += 32; gb += 32;

    const int kg = lane >> 4, r = lane & 15;
    const int NT = DIN / 32;   // 64
    int cur = 0, c2 = 2;       // read buffer, stage-target buffer
    for (int t = 0; t < NT; ++t) {
        if (t < NT - 2) {
            ISSUE4(AsF + c2 * 4096 + tid * 8, BsF + c2 * 4096 + tid * 8, ga, gb);
            ga += 32; gb += 32;
            asm volatile("s_waitcnt vmcnt(8)" ::: "memory");   // stage(t) landed; t+1,t+2 in flight
        } else if (t == NT - 2) {
            asm volatile("s_waitcnt vmcnt(4)" ::: "memory");   // stage(t) landed; t+1 in flight
        } else {
            asm volatile("s_waitcnt vmcnt(0)" ::: "memory");   // drain
        }
        __builtin_amdgcn_s_barrier();                          // all waves' stage(t) in LDS
        asm volatile("" ::: "memory");

        const unsigned short* Ab = AsF + cur * 4096;
        const unsigned short* Bb = BsF + cur * 4096;
        bf16x8 af[4], bfm[4];
        #pragma unroll
        for (int mi = 0; mi < 4; mi++)
            af[mi] = *(const bf16x8*)&Ab[(kg * 128 + wr * 64 + mi * 16 + r) * 8];
        #pragma unroll
        for (int ni = 0; ni < 4; ni++)
            bfm[ni] = *(const bf16x8*)&Bb[(kg * 128 + wc * 64 + ni * 16 + r) * 8];
        #pragma unroll
        for (int mi = 0; mi < 4; mi++)
            #pragma unroll
            for (int ni = 0; ni < 4; ni++)
                acc[mi][ni] = __builtin_amdgcn_mfma_f32_16x16x32_bf16(af[mi], bfm[ni], acc[mi][ni], 0, 0, 0);

        asm volatile("" ::: "memory");
        __builtin_amdgcn_s_barrier();   // all waves done reading buf cur -> it may be restaged
        cur = (cur == 2) ? 0 : cur + 1;
        c2  = (c2  == 2) ? 0 : c2  + 1;
    }

    const int r16 = lane & 15, quad = lane >> 4;
    float bv[4];
    #pragma unroll
    for (int ni = 0; ni < 4; ni++) bv[ni] = bias[bcol + wc * 64 + ni * 16 + r16];

    if (EPILOGUE == 0) {
        #pragma unroll
        for (int mi = 0; mi < 4; mi++) {
            #pragma unroll
            for (int j = 0; j < 4; j++) {
                int row = brow + wr * 64 + mi * 16 + quad * 4 + j;
                int lab = labels[row];
                #pragma unroll
                for (int ni = 0; ni < 4; ni++) {
                    float e = acc[mi][ni][j] + bv[ni];
                    atomicAdd(&proto_sums[(size_t)lab * DEMB + bcol + wc * 64 + ni * 16 + r16], e);
                }
            }
        }
    } else {
        #pragma unroll
        for (int mi = 0; mi < 4; mi++) {
            float s0 = 0.f, s1 = 0.f, s2 = 0.f, s3 = 0.f;
            #pragma unroll
            for (int j = 0; j < 4; j++) {
                int row = brow + wr * 64 + mi * 16 + quad * 4 + j;
                float sj = 0.f;
                #pragma unroll
                for (int ni = 0; ni < 4; ni++) {
                    float e = acc[mi][ni][j] + bv[ni];
                    emb_out[(size_t)row * DEMB + bcol + wc * 64 + ni * 16 + r16] = f2bf(e);
                    sj += e * e;
                }
                if (j == 0) s0 = sj; else if (j == 1) s1 = sj; else if (j == 2) s2 = sj; else s3 = sj;
            }
            float sv[4] = { s0, s1, s2, s3 };
            #pragma unroll
            for (int j = 0; j < 4; j++) {
                float v = sv[j];
                v += __shfl_xor(v, 1);
                v += __shfl_xor(v, 2);
                v += __shfl_xor(v, 4);
                v += __shfl_xor(v, 8);
                if (r16 == 0) {
                    int row = brow + wr * 64 + mi * 16 + quad * 4 + j;
                    atomicAdd(&qsq[row], v);
                }
            }
        }
    }
}

// ---------------- prototype normalize ----------------
__global__ void proto_norm(const float* __restrict__ proto_sums,
                           const int* __restrict__ labels,
                           unsigned short* __restrict__ proto_bf16,
                           float* __restrict__ psq) {
    int c = blockIdx.x;
    int tid = threadIdx.x;
    int cnt = 0;
    for (int i = tid; i < NSUP; i += 256) cnt += (labels[i] == c) ? 1 : 0;
    #pragma unroll
    for (int m = 1; m < 64; m <<= 1) cnt += __shfl_xor(cnt, m);
    __shared__ int warp_cnt[4];
    __shared__ float warp_ss[4];
    if ((tid & 63) == 0) warp_cnt[tid >> 6] = cnt;
    __syncthreads();
    int total = warp_cnt[0] + warp_cnt[1] + warp_cnt[2] + warp_cnt[3];
    float inv = 1.0f / (float)total;
    float ss = 0.f;
    for (int j = tid; j < DEMB; j += 256) {
        float p = proto_sums[(size_t)c * DEMB + j] * inv;
        proto_bf16[(size_t)c * DEMB + j] = f2bf(p);
        ss += p * p;
    }
    #pragma unroll
    for (int m = 1; m < 64; m <<= 1) ss += __shfl_xor(ss, m);
    if ((tid & 63) == 0) warp_ss[tid >> 6] = ss;
    __syncthreads();
    if (tid == 0) psq[c] = warp_ss[0] + warp_ss[1] + warp_ss[2] + warp_ss[3];
}

// ---------------- scores: out[q][c] = -sqrt(max(qsq+psq-2*dot,0)) ----------------
__global__ __launch_bounds__(256) void scores_kernel(
    const unsigned short* __restrict__ q_emb,
    const unsigned short* __restrict__ protos,
    const float* __restrict__ qsq, const float* __restrict__ psq,
    float* __restrict__ out)
{
    int tid = threadIdx.x, lane = tid & 63, wid = tid >> 6;
    int q0 = blockIdx.x * 64 + wid * 16;
    int r = lane & 15, quad = lane >> 4;
    f32x4 acc[4];
    #pragma unroll
    for (int i = 0; i < 4; i++) acc[i] = (f32x4)(0.f);
    const unsigned short* arow = q_emb + (size_t)(q0 + r) * DEMB + quad * 8;
    for (int k0 = 0; k0 < DEMB; k0 += 32) {
        bf16x8 a = *(const bf16x8*)(arow + k0);
        #pragma unroll
        for (int ni = 0; ni < 4; ni++) {
            bf16x8 bfrag = *(const bf16x8*)(protos + (size_t)(ni * 16 + r) * DEMB + k0 + quad * 8);
            acc[ni] = __builtin_amdgcn_mfma_f32_16x16x32_bf16(a, bfrag, acc[ni], 0, 0, 0);
        }
    }
    #pragma unroll
    for (int ni = 0; ni < 4; ni++) {
        int c = ni * 16 + r;
        float ps = psq[c];
        #pragma unroll
        for (int j = 0; j < 4; j++) {
            int row = q0 + quad * 4 + j;
            float d2 = qsq[row] + ps - 2.0f * acc[ni][j];
            d2 = fmaxf(d2, 0.0f);
            out[(size_t)row * NWAY + c] = -sqrtf(d2);
        }
    }
}

// ---------------- launch ----------------
extern "C" void kernel_launch(void* const* d_in, const int* in_sizes, int n_in,
                              void* d_out, int out_size, void* d_ws, size_t ws_size,
                              hipStream_t stream) {
    const float* support = (const float*)d_in[0];
    const float* query   = (const float*)d_in[1];
    const int*   labels  = (const int*)d_in[2];
    // d_in[3] = n_way (assumed 64)
    const float* W       = (const float*)d_in[4];
    const float* bias    = (const float*)d_in[5];
    float* out = (float*)d_out;

    char* ws = (char*)d_ws;
    unsigned short* q_bf     = (unsigned short*)(ws);                 // 67108864 B
    unsigned short* s_bf     = (unsigned short*)(ws + 67108864);      //  8388608 B
    unsigned short* Wt       = (unsigned short*)(ws + 75497472);      //  4194304 B
    unsigned short* q_emb    = (unsigned short*)(ws + 79691776);      // 33554432 B
    float*          proto_sums = (float*)(ws + 113246208);            //   262144 B
    unsigned short* proto_bf = (unsigned short*)(ws + 113508352);     //   131072 B
    float*          qsq      = (float*)(ws + 113639424);              //    65536 B
    float*          psq      = (float*)(ws + 113704960);              //      256 B

    hipMemsetAsync(proto_sums, 0, (size_t)NWAY * DEMB * sizeof(float), stream);
    hipMemsetAsync(qsq, 0, (size_t)NQRY * sizeof(float), stream);

    cvt_f32_bf16<<<2048, 256, 0, stream>>>(query, q_bf, NQRY * DIN);
    cvt_f32_bf16<<<512, 256, 0, stream>>>(support, s_bf, NSUP * DIN);
    dim3 tg(DEMB / 32, DIN / 32);
    cvt_transpose<<<tg, 256, 0, stream>>>(W, Wt);

    gemm_emb<0><<<(NSUP / 128) * (DEMB / 128), 256, 0, stream>>>(
        s_bf, Wt, bias, labels, proto_sums, nullptr, nullptr);
    proto_norm<<<NWAY, 256, 0, stream>>>(proto_sums, labels, proto_bf, psq);
    gemm_emb<1><<<(NQRY / 128) * (DEMB / 128), 256, 0, stream>>>(
        q_bf, Wt, bias, nullptr, nullptr, q_emb, qsq);
    scores_kernel<<<NQRY / 64, 256, 0, stream>>>(q_emb, proto_bf, qsq, psq, out);
}

// Round 11
// 250.869 us; speedup vs baseline: 1.1458x; 1.1458x over previous
//
#include <hip/hip_runtime.h>
#include <hip/hip_bf16.h>
#include <stdint.h>

#define DIN 2048
#define DEMB 1024
#define NSUP 2048
#define NQRY 16384
#define NWAY 64

typedef __attribute__((ext_vector_type(8))) short bf16x8;
typedef __attribute__((ext_vector_type(4))) float f32x4;

__device__ inline unsigned short f2bf(float f) {
    union { float f; uint32_t u; } v; v.f = f;
    uint32_t u = v.u;
    uint32_t r = (u + 0x7FFFu + ((u >> 16) & 1u)) >> 16;
    return (unsigned short)r;
}

#define GLL(g, l) __builtin_amdgcn_global_load_lds(                                   \
    (const __attribute__((address_space(1))) void*)(g),                               \
    (__attribute__((address_space(3))) void*)(l), 16, 0, 0)

// ---------------- conversion kernels ----------------

__global__ void cvt_f32_bf16(const float* __restrict__ in, unsigned short* __restrict__ out, int n) {
    int i = (blockIdx.x * blockDim.x + threadIdx.x) * 4;
    int stride = gridDim.x * blockDim.x * 4;
    for (; i < n; i += stride) {
        float4 v = *(const float4*)(in + i);
        ushort4 o;
        o.x = f2bf(v.x); o.y = f2bf(v.y); o.z = f2bf(v.z); o.w = f2bf(v.w);
        *(ushort4*)(out + i) = o;
    }
}

// W [DIN][DEMB] f32  ->  Wt [DEMB][DIN] bf16
__global__ void cvt_transpose(const float* __restrict__ W, unsigned short* __restrict__ Wt) {
    __shared__ float tile[32][33];
    int c0 = blockIdx.x * 32;
    int r0 = blockIdx.y * 32;
    int tc = threadIdx.x & 31, tr = threadIdx.x >> 5;
    #pragma unroll
    for (int i = 0; i < 4; i++)
        tile[tr + 8*i][tc] = W[(size_t)(r0 + tr + 8*i) * DEMB + c0 + tc];
    __syncthreads();
    #pragma unroll
    for (int i = 0; i < 4; i++)
        Wt[(size_t)(c0 + tr + 8*i) * DIN + r0 + tc] = f2bf(tile[tc][tr + 8*i]);
}

// ---------------- embedding GEMM: BM=128, BN=32*NNI, BK=32, 2-buf counted-vmcnt ----------
// NNI=8 (query): BN=256, 32 MFMA/wave/K-step -- 2x FLOPs per barrier pair vs r9.
// NNI=4 (support): BN=128, identical to the verified r9 shape.
// Schedule (r9-verified): issue stage(t+1), s_waitcnt vmcnt(stage_loads) keeps it in
// flight across the barrier; only stage(t) must land. Hoisted staging pointers.
// EPILOGUE 0: support -> atomicAdd proto_sums[label[row]][col]
// EPILOGUE 1: query   -> store bf16 emb + atomicAdd row sumsq

template<int EPILOGUE, int NNI>
__global__ __launch_bounds__(256, 2) void gemm_emb(
    const unsigned short* __restrict__ A,
    const unsigned short* __restrict__ Bt,
    const float* __restrict__ bias,
    const int* __restrict__ labels,
    float* __restrict__ proto_sums,
    unsigned short* __restrict__ emb_out,
    float* __restrict__ qsq)
{
    constexpr int BN = 32 * NNI;          // 256 or 128
    constexpr int ASZ = 4 * 128 * 8;      // 4096 elems / buf
    constexpr int BSZ = 4 * BN * 8;       // 8192 (NNI=8) or 4096 elems / buf
    __shared__ __attribute__((aligned(16))) unsigned short AsF[2 * ASZ];
    __shared__ __attribute__((aligned(16))) unsigned short BsF[2 * BSZ];

    const int tid = threadIdx.x;
    const int nblk = DEMB / BN;           // 4 (query) or 8 (support)
    // XCD-panel grouping (verified r8: FETCH 268->66MB). gridDim.x % 8 == 0.
    const int h = blockIdx.x;
    const int cpx = (int)(gridDim.x >> 3);
    const int wg = (h & 7) * cpx + (h >> 3);
    const int bx = wg % nblk;
    const int by = wg / nblk;
    const int brow = by * 128, bcol = bx * BN;
    const int lane = tid & 63, wid = tid >> 6;
    const int wr = wid >> 1, wc = wid & 1;

    // hoisted staging pointers
    const int rowa = tid & 127, kga = tid >> 7;
    const unsigned short* ga = A + (size_t)(brow + rowa) * DIN + kga * 8;
    const unsigned short* gb;
    if constexpr (NNI == 8) {
        gb = Bt + (size_t)(bcol + tid) * DIN;          // 4 loads: +0,8,16,24 elems
    } else {
        int rowb = tid & 127, kgb = tid >> 7;
        gb = Bt + (size_t)(bcol + rowb) * DIN + kgb * 8;  // 2 loads: +0,+16 elems
    }

    f32x4 acc[4][NNI];
    #pragma unroll
    for (int i = 0; i < 4; i++)
        #pragma unroll
        for (int j = 0; j < NNI; j++) acc[i][j] = (f32x4)(0.f);

    auto stageAB = [&](int buf) {
        unsigned short* la = AsF + buf * ASZ + tid * 8;
        unsigned short* lb = BsF + buf * BSZ + tid * 8;
        GLL(ga, la); GLL(ga + 16, la + 2048);
        if constexpr (NNI == 8) {
            GLL(gb, lb); GLL(gb + 8, lb + 2048); GLL(gb + 16, lb + 4096); GLL(gb + 24, lb + 6144);
        } else {
            GLL(gb, lb); GLL(gb + 16, lb + 2048);
        }
        ga += 32; gb += 32;
    };

    // prologue: stage tile 0 into buf 0
    stageAB(0);

    const int kg = lane >> 4, r = lane & 15;
    const int NT = DIN / 32;   // 64
    for (int t = 0; t < NT; ++t) {
        const int cur = t & 1;
        if (t < NT - 1) {
            stageAB(cur ^ 1);   // stays in flight across the barrier
            if constexpr (NNI == 8) asm volatile("s_waitcnt vmcnt(6)" ::: "memory");
            else                    asm volatile("s_waitcnt vmcnt(4)" ::: "memory");
        } else {
            asm volatile("s_waitcnt vmcnt(0)" ::: "memory");
        }
        __builtin_amdgcn_s_barrier();
        asm volatile("" ::: "memory");

        const unsigned short* Ab = AsF + cur * ASZ;
        const unsigned short* Bb = BsF + cur * BSZ;
        bf16x8 af[4], bfm[NNI];
        #pragma unroll
        for (int mi = 0; mi < 4; mi++)
            af[mi] = *(const bf16x8*)&Ab[(kg * 128 + wr * 64 + mi * 16 + r) * 8];
        #pragma unroll
        for (int ni = 0; ni < NNI; ni++)
            bfm[ni] = *(const bf16x8*)&Bb[(kg * BN + wc * (BN / 2) + ni * 16 + r) * 8];
        #pragma unroll
        for (int mi = 0; mi < 4; mi++)
            #pragma unroll
            for (int ni = 0; ni < NNI; ni++)
                acc[mi][ni] = __builtin_amdgcn_mfma_f32_16x16x32_bf16(af[mi], bfm[ni], acc[mi][ni], 0, 0, 0);

        asm volatile("" ::: "memory");
        __builtin_amdgcn_s_barrier();   // all waves done reading buf cur -> may be restaged
    }

    const int r16 = lane & 15, quad = lane >> 4;
    float bv[NNI];
    #pragma unroll
    for (int ni = 0; ni < NNI; ni++) bv[ni] = bias[bcol + wc * (BN / 2) + ni * 16 + r16];

    if (EPILOGUE == 0) {
        #pragma unroll
        for (int mi = 0; mi < 4; mi++) {
            #pragma unroll
            for (int j = 0; j < 4; j++) {
                int row = brow + wr * 64 + mi * 16 + quad * 4 + j;
                int lab = labels[row];
                #pragma unroll
                for (int ni = 0; ni < NNI; ni++) {
                    float e = acc[mi][ni][j] + bv[ni];
                    atomicAdd(&proto_sums[(size_t)lab * DEMB + bcol + wc * (BN / 2) + ni * 16 + r16], e);
                }
            }
        }
    } else {
        #pragma unroll
        for (int mi = 0; mi < 4; mi++) {
            float s0 = 0.f, s1 = 0.f, s2 = 0.f, s3 = 0.f;
            #pragma unroll
            for (int j = 0; j < 4; j++) {
                int row = brow + wr * 64 + mi * 16 + quad * 4 + j;
                float sj = 0.f;
                #pragma unroll
                for (int ni = 0; ni < NNI; ni++) {
                    float e = acc[mi][ni][j] + bv[ni];
                    emb_out[(size_t)row * DEMB + bcol + wc * (BN / 2) + ni * 16 + r16] = f2bf(e);
                    sj += e * e;
                }
                if (j == 0) s0 = sj; else if (j == 1) s1 = sj; else if (j == 2) s2 = sj; else s3 = sj;
            }
            float sv[4] = { s0, s1, s2, s3 };
            #pragma unroll
            for (int j = 0; j < 4; j++) {
                float v = sv[j];
                v += __shfl_xor(v, 1);
                v += __shfl_xor(v, 2);
                v += __shfl_xor(v, 4);
                v += __shfl_xor(v, 8);
                if (r16 == 0) {
                    int row = brow + wr * 64 + mi * 16 + quad * 4 + j;
                    atomicAdd(&qsq[row], v);
                }
            }
        }
    }
}

// ---------------- prototype normalize ----------------
__global__ void proto_norm(const float* __restrict__ proto_sums,
                           const int* __restrict__ labels,
                           unsigned short* __restrict__ proto_bf16,
                           float* __restrict__ psq) {
    int c = blockIdx.x;
    int tid = threadIdx.x;
    int cnt = 0;
    for (int i = tid; i < NSUP; i += 256) cnt += (labels[i] == c) ? 1 : 0;
    #pragma unroll
    for (int m = 1; m < 64; m <<= 1) cnt += __shfl_xor(cnt, m);
    __shared__ int warp_cnt[4];
    __shared__ float warp_ss[4];
    if ((tid & 63) == 0) warp_cnt[tid >> 6] = cnt;
    __syncthreads();
    int total = warp_cnt[0] + warp_cnt[1] + warp_cnt[2] + warp_cnt[3];
    float inv = 1.0f / (float)total;
    float ss = 0.f;
    for (int j = tid; j < DEMB; j += 256) {
        float p = proto_sums[(size_t)c * DEMB + j] * inv;
        proto_bf16[(size_t)c * DEMB + j] = f2bf(p);
        ss += p * p;
    }
    #pragma unroll
    for (int m = 1; m < 64; m <<= 1) ss += __shfl_xor(ss, m);
    if ((tid & 63) == 0) warp_ss[tid >> 6] = ss;
    __syncthreads();
    if (tid == 0) psq[c] = warp_ss[0] + warp_ss[1] + warp_ss[2] + warp_ss[3];
}

// ---------------- scores: out[q][c] = -sqrt(max(qsq+psq-2*dot,0)) ----------------
__global__ __launch_bounds__(256) void scores_kernel(
    const unsigned short* __restrict__ q_emb,
    const unsigned short* __restrict__ protos,
    const float* __restrict__ qsq, const float* __restrict__ psq,
    float* __restrict__ out)
{
    int tid = threadIdx.x, lane = tid & 63, wid = tid >> 6;
    int q0 = blockIdx.x * 64 + wid * 16;
    int r = lane & 15, quad = lane >> 4;
    f32x4 acc[4];
    #pragma unroll
    for (int i = 0; i < 4; i++) acc[i] = (f32x4)(0.f);
    const unsigned short* arow = q_emb + (size_t)(q0 + r) * DEMB + quad * 8;
    for (int k0 = 0; k0 < DEMB; k0 += 32) {
        bf16x8 a = *(const bf16x8*)(arow + k0);
        #pragma unroll
        for (int ni = 0; ni < 4; ni++) {
            bf16x8 bfrag = *(const bf16x8*)(protos + (size_t)(ni * 16 + r) * DEMB + k0 + quad * 8);
            acc[ni] = __builtin_amdgcn_mfma_f32_16x16x32_bf16(a, bfrag, acc[ni], 0, 0, 0);
        }
    }
    #pragma unroll
    for (int ni = 0; ni < 4; ni++) {
        int c = ni * 16 + r;
        float ps = psq[c];
        #pragma unroll
        for (int j = 0; j < 4; j++) {
            int row = q0 + quad * 4 + j;
            float d2 = qsq[row] + ps - 2.0f * acc[ni][j];
            d2 = fmaxf(d2, 0.0f);
            out[(size_t)row * NWAY + c] = -sqrtf(d2);
        }
    }
}

// ---------------- launch ----------------
extern "C" void kernel_launch(void* const* d_in, const int* in_sizes, int n_in,
                              void* d_out, int out_size, void* d_ws, size_t ws_size,
                              hipStream_t stream) {
    const float* support = (const float*)d_in[0];
    const float* query   = (const float*)d_in[1];
    const int*   labels  = (const int*)d_in[2];
    // d_in[3] = n_way (assumed 64)
    const float* W       = (const float*)d_in[4];
    const float* bias    = (const float*)d_in[5];
    float* out = (float*)d_out;

    char* ws = (char*)d_ws;
    unsigned short* q_bf     = (unsigned short*)(ws);                 // 67108864 B
    unsigned short* s_bf     = (unsigned short*)(ws + 67108864);      //  8388608 B
    unsigned short* Wt       = (unsigned short*)(ws + 75497472);      //  4194304 B
    unsigned short* q_emb    = (unsigned short*)(ws + 79691776);      // 33554432 B
    float*          proto_sums = (float*)(ws + 113246208);            //   262144 B
    unsigned short* proto_bf = (unsigned short*)(ws + 113508352);     //   131072 B
    float*          qsq      = (float*)(ws + 113639424);              //    65536 B
    float*          psq      = (float*)(ws + 113704960);              //      256 B

    hipMemsetAsync(proto_sums, 0, (size_t)NWAY * DEMB * sizeof(float), stream);
    hipMemsetAsync(qsq, 0, (size_t)NQRY * sizeof(float), stream);

    cvt_f32_bf16<<<2048, 256, 0, stream>>>(query, q_bf, NQRY * DIN);
    cvt_f32_bf16<<<512, 256, 0, stream>>>(support, s_bf, NSUP * DIN);
    dim3 tg(DEMB / 32, DIN / 32);
    cvt_transpose<<<tg, 256, 0, stream>>>(W, Wt);

    gemm_emb<0, 4><<<(NSUP / 128) * (DEMB / 128), 256, 0, stream>>>(
        s_bf, Wt, bias, labels, proto_sums, nullptr, nullptr);
    proto_norm<<<NWAY, 256, 0, stream>>>(proto_sums, labels, proto_bf, psq);
    gemm_emb<1, 8><<<(NQRY / 128) * (DEMB / 256), 256, 0, stream>>>(
        q_bf, Wt, bias, nullptr, nullptr, q_emb, qsq);
    scores_kernel<<<NQRY / 64, 256, 0, stream>>>(q_emb, proto_bf, qsq, psq, out);
}